// Round 15
// baseline (185.829 us; speedup 1.0000x reference)
//
#include <hip/hip_runtime.h>
#include <math.h>

#define B_ 4
#define T_ 2048
#define C_ 1024
#define H_ 16
#define D_ 64
#define M_ (B_*T_)      // 8192
#define N1_ (3*C_)      // 3072

typedef __attribute__((ext_vector_type(8))) short bf16x8;
typedef __attribute__((ext_vector_type(4))) short bf16x4;
typedef __attribute__((ext_vector_type(4))) float f32x4;
typedef __attribute__((ext_vector_type(16))) float f32x16;

__device__ __forceinline__ short f2bf(float f){
  union { float f; unsigned u; } v; v.f = f;
  unsigned r = (v.u + 0x7fffu + ((v.u >> 16) & 1u)) >> 16;
  return (short)r;
}

__device__ __forceinline__ unsigned cvtpk(float lo, float hi){
  unsigned r;
  asm("v_cvt_pk_bf16_f32 %0, %1, %2" : "=v"(r) : "v"(lo), "v"(hi));
  return r;
}

// v_permlane32_swap_b32: a' = {a[0:31], b[0:31]}, b' = {a[32:63], b[32:63]}
__device__ __forceinline__ void plswap(unsigned &a, unsigned &b){
  asm volatile("v_permlane32_swap_b32 %0, %1" : "+v"(a), "+v"(b));
}
__device__ __forceinline__ float xhalf_add(float x){
  unsigned a = __float_as_uint(x), b = a;
  asm volatile("v_permlane32_swap_b32 %0, %1" : "+v"(a), "+v"(b));
  return __uint_as_float(a) + __uint_as_float(b);
}

__device__ __forceinline__ void gll16(const void* g, void* l){
  __builtin_amdgcn_global_load_lds((const __attribute__((address_space(1))) void*)g,
                                   (__attribute__((address_space(3))) void*)l, 16, 0, 0);
}

// ---- convert x (f32) -> bf16 ----
__global__ __launch_bounds__(256) void convx(const float* __restrict__ x, short* __restrict__ xb, int n){
  int i = (blockIdx.x*256 + threadIdx.x)*8;
  if (i >= n) return;
  float4 a = *(const float4*)(x+i), b = *(const float4*)(x+i+4);
  bf16x8 o;
  o[0]=f2bf(a.x); o[1]=f2bf(a.y); o[2]=f2bf(a.z); o[3]=f2bf(a.w);
  o[4]=f2bf(b.x); o[5]=f2bf(b.y); o[6]=f2bf(b.z); o[7]=f2bf(b.w);
  *(bf16x8*)(xb+i) = o;
}

// ---- transpose W (K,N) f32 -> Wt (N,K) bf16 ----
__global__ __launch_bounds__(256) void transw(const float* __restrict__ W, short* __restrict__ Wt, int K, int N){
  __shared__ float tl[64][72];
  int tid = threadIdx.x;
  int n0 = blockIdx.x*64, k0 = blockIdx.y*64;
  #pragma unroll
  for (int i=0;i<4;i++){
    int row = (tid>>4) + i*16;
    int col4 = (tid&15)*4;
    float4 v = *(const float4*)&W[(size_t)(k0+row)*N + n0 + col4];
    *(float4*)&tl[row][col4] = v;
  }
  __syncthreads();
  #pragma unroll
  for (int i=0;i<2;i++){
    int nr = (tid>>3) + i*32;
    int ch = tid&7;
    bf16x8 o;
    #pragma unroll
    for (int e=0;e<8;e++) o[e] = f2bf(tl[ch*8+e][nr]);
    *(bf16x8*)&Wt[(size_t)(n0+nr)*K + k0 + ch*8] = o;
  }
}

// ---- GEMM v2: 256x128 tile, BK=64, 8 waves, triple-buffered LDS, counted vmcnt ----
// OUTBF=1 (QKV): Q cols pre-scaled by cexp; V cols written transposed to vtb directly.
template<int OUTBF>
__global__ __launch_bounds__(512) void gemm_bt(const short* __restrict__ A, const short* __restrict__ Bt,
           const float* __restrict__ bias, short* __restrict__ outb, float* __restrict__ outf,
           short* __restrict__ vtb, int M, int N, int K)
{
  __shared__ __attribute__((aligned(128))) char LDSC[147456];  // A:3x32KB @0, B:3x16KB @98304
  const int tid = threadIdx.x;
  const int wv = tid>>6, ln = tid&63;
  const int lnr = ln&15, lg = ln>>4;
  const int wm = wv>>1, wn = wv&1;
  const int nx = gridDim.x;
  const int nwg = nx*gridDim.y;
  const int lin = blockIdx.x + nx*blockIdx.y;
  const int swz = (lin&7)*(nwg>>3) + (lin>>3);
  const int m0 = (swz/nx)*256, n0 = (swz%nx)*128;

  const int srA = tid>>3;
  const int sg  = (tid&7) ^ (srA&7);
  const short* Ag = A  + (size_t)(m0 + srA)*K + sg*8;
  const short* Bg = Bt + (size_t)(n0 + srA)*K + sg*8;

  const int fsw = (lg ^ (lnr&7))<<4;
  const int aln = (wm*64 + lnr)*128 + fsw;
  const int bln = (wn*64 + lnr)*128 + fsw;

  auto STAGE = [&](int kt, int bi){
    const short* a = Ag + kt*64;
    const short* b = Bg + kt*64;
    char* ab = LDSC + bi*32768 + wv*1024;
    char* bb = LDSC + 98304 + bi*16384 + wv*1024;
    gll16(a,                ab);
    gll16(a + (size_t)64*K, ab + 8192);
    gll16(a + (size_t)128*K, ab + 16384);
    gll16(a + (size_t)192*K, ab + 24576);
    gll16(b,                bb);
    gll16(b + (size_t)64*K, bb + 8192);
  };

  f32x4 acc[4][4];
  #pragma unroll
  for (int i=0;i<4;i++)
    #pragma unroll
    for (int j=0;j<4;j++) acc[i][j] = (f32x4){0.f,0.f,0.f,0.f};

  const int NT = K >> 6;
  STAGE(0, 0);
  STAGE(1, 1);
  asm volatile("s_waitcnt vmcnt(6)" ::: "memory");
  __builtin_amdgcn_sched_barrier(0);
  __builtin_amdgcn_s_barrier();
  __builtin_amdgcn_sched_barrier(0);

  int cb = 0, sb = 2;
  #pragma unroll 1
  for (int kt = 0; kt < NT; kt++){
    if (kt + 2 < NT) STAGE(kt + 2, sb);

    const char* ab = LDSC + cb*32768;
    const char* bb = LDSC + 98304 + cb*16384;
    bf16x8 af[4][2], bfr[4][2];
    #pragma unroll
    for (int mi=0;mi<4;mi++)
      #pragma unroll
      for (int ks=0;ks<2;ks++)
        af[mi][ks] = *(const bf16x8*)(ab + ((aln + mi*2048) ^ (ks<<6)));
    #pragma unroll
    for (int ni=0;ni<4;ni++)
      #pragma unroll
      for (int ks=0;ks<2;ks++)
        bfr[ni][ks] = *(const bf16x8*)(bb + ((bln + ni*2048) ^ (ks<<6)));

    __builtin_amdgcn_s_setprio(1);
    #pragma unroll
    for (int mi=0;mi<4;mi++)
      #pragma unroll
      for (int ni=0;ni<4;ni++)
        #pragma unroll
        for (int ks=0;ks<2;ks++)
          acc[mi][ni] = __builtin_amdgcn_mfma_f32_16x16x32_bf16(af[mi][ks], bfr[ni][ks], acc[mi][ni], 0,0,0);
    __builtin_amdgcn_s_setprio(0);

    if (kt < NT-1){
      __builtin_amdgcn_sched_barrier(0);
      if (kt < NT-2){ asm volatile("s_waitcnt vmcnt(6)" ::: "memory"); }
      else          { asm volatile("s_waitcnt vmcnt(0)" ::: "memory"); }
      __builtin_amdgcn_sched_barrier(0);
      __builtin_amdgcn_s_barrier();
      __builtin_amdgcn_sched_barrier(0);
    }
    cb = (cb==2) ? 0 : cb+1;
    sb = (sb==2) ? 0 : sb+1;
  }

  #pragma unroll
  for (int mi=0;mi<4;mi++){
    #pragma unroll
    for (int ni=0;ni<4;ni++){
      int col = n0 + wn*64 + ni*16 + lnr;
      float bv = bias[col];
      #pragma unroll
      for (int r=0;r<4;r++){
        int row = m0 + wm*64 + mi*16 + lg*4 + r;
        float v = acc[mi][ni][r] + bv;
        if (OUTBF){
          if (col >= 2*C_){
            // V: write transposed to vt (bh, d, t) directly
            int cc = col - 2*C_;
            int bb2 = row >> 11, tt = row & (T_-1);
            vtb[((size_t)((bb2*H_ + (cc>>6))*D_ + (cc&63)))*T_ + tt] = f2bf(v);
          } else {
            if (col < C_) v *= 0.18033688f;   // pre-scale Q into exp2 domain
            outb[(size_t)row*N + col] = f2bf(v);
          }
        } else {
          outf[(size_t)row*N + col] = v;
        }
      }
    }
  }
}

// ---- flash attention v14: single-buffer body (best), exp2-folded softmax,
// unpaired LPT grid (1024 blocks: bh=64 x c=16), 4 waves, 16 KB LDS.
__global__ __launch_bounds__(256) void attn14(const short* __restrict__ qkv, const short* __restrict__ vt,
           const int* __restrict__ mask, short* __restrict__ yb)
{
  __shared__ short Ks[64*64];   // 8 KB, rows = key, cols swizzled
  __shared__ short Vs[64*64];   // 8 KB, rows = d,   cols swizzled
  const int tid = threadIdx.x;
  const int wv = tid>>6, ln = tid&63;
  const int l31 = ln & 31, hi = ln >> 5;
  const int bh = blockIdx.x, b = bh>>4, hd = bh&15;
  const int c = 15 - (int)blockIdx.y;    // LPT: heavy chunks dispatch first
  const float MC = 11.541561f;           // fixed softmax offset (exp2 domain)

  // staging map: thread -> (row 0..31, pre-swizzled 16B col-block)
  const int srow = tid>>3;
  const int scol = (tid&7) ^ (srow&7);
  const short* kgb = qkv + (size_t)(b*T_ + srow)*N1_ + C_ + hd*D_ + scol*8;
  const short* vgb = vt  + (size_t)((bh<<6) + srow)*T_ + scol*8;
  // fragment LDS byte addrs (loop-invariant): row l31, 16B-block (2i+hi)^(row&7)
  int fa[4];
  #pragma unroll
  for (int i=0;i<4;i++)
    fa[i] = l31*128 + ((((i<<1)+hi) ^ (l31&7)) << 4);

  char* ksb = (char*)Ks;
  char* vsb = (char*)Vs;

  const int q0w = c*128 + wv*32;
  const int ntb  = 2*c + 2;                 // block staged tiles
  const int myNt = 2*c + 1 + (wv>>1);       // wave's needed tiles

  // Q fragments (B-operand; pre-scaled by cexp in GEMM epilogue)
  bf16x8 qf[4];
  const short* qbase = qkv + (size_t)(b*T_ + q0w + l31)*N1_ + hd*D_ + hi*8;
  #pragma unroll
  for (int ds=0; ds<4; ds++) qf[ds] = *(const bf16x8*)(qbase + ds*16);

  f32x16 o0, o1;
  #pragma unroll
  for (int r=0;r<16;r++){ o0[r]=0.f; o1[r]=0.f; }
  float lsum = 0.f;

  #pragma unroll 1
  for (int jt = 0; jt < ntb; jt++){
    const int j0 = jt << 6;

    // mask (coalesced) + cooperative stage of K,V tiles
    int mval = mask[b*T_ + j0 + ln];
    const short* kg = kgb + (size_t)j0*N1_;
    const short* vg = vgb + j0;
    gll16(kg,                    ksb + wv*1024);
    gll16(kg + (size_t)32*N1_,   ksb + 4096 + wv*1024);
    gll16(vg,                    vsb + wv*1024);
    gll16(vg + (size_t)32*T_,    vsb + 4096 + wv*1024);
    unsigned long long bm = __ballot(mval != 0);
    __syncthreads();   // staged tile visible

    if (jt < myNt){
      // ---- QK^T (swapped) from LDS; acc init -MC folds softmax offset ----
      f32x16 s0, s1;
      #pragma unroll
      for (int r=0;r<16;r++){ s0[r]=-MC; s1[r]=-MC; }
      __builtin_amdgcn_s_setprio(1);
      #pragma unroll
      for (int ds=0; ds<4; ds++){
        bf16x8 k0 = *(const bf16x8*)(ksb + fa[ds]);
        bf16x8 k1 = *(const bf16x8*)(ksb + fa[ds] + 4096);
        s0 = __builtin_amdgcn_mfma_f32_32x32x16_bf16(k0, qf[ds], s0, 0,0,0);
        s1 = __builtin_amdgcn_mfma_f32_32x32x16_bf16(k1, qf[ds], s1, 0,0,0);
      }
      __builtin_amdgcn_s_setprio(0);

      // ---- masking (exp2 domain; -inf -> p=0) ----
      const int qglob = q0w + l31;
      const bool allm = (bm == ~0ull);
      if (!allm){
        #pragma unroll
        for (int r=0;r<16;r++){
          int kr = (r&3) + 8*(r>>2) + 4*hi;
          bool ok0 = (j0 + kr      <= qglob) && ((bm >> kr) & 1);
          bool ok1 = (j0 + kr + 32 <= qglob) && ((bm >> (kr+32)) & 1);
          s0[r] = ok0 ? s0[r] : -INFINITY;
          s1[r] = ok1 ? s1[r] : -INFINITY;
        }
      } else if (j0 + 63 > q0w){   // diagonal tile: causal only
        #pragma unroll
        for (int r=0;r<16;r++){
          int kr = (r&3) + 8*(r>>2) + 4*hi;
          s0[r] = (j0 + kr      <= qglob) ? s0[r] : -INFINITY;
          s1[r] = (j0 + kr + 32 <= qglob) ? s1[r] : -INFINITY;
        }
      }

      // ---- p = exp2(s) directly ----
      #pragma unroll
      for (int r=0;r<16;r++){
        s0[r] = __builtin_amdgcn_exp2f(s0[r]);
        s1[r] = __builtin_amdgcn_exp2f(s1[r]);
      }
      // tile sum
      float u[8];
      #pragma unroll
      for (int i=0;i<8;i++) u[i] = (s0[i]+s0[i+8]) + (s1[i]+s1[i+8]);
      #pragma unroll
      for (int i=0;i<4;i++) u[i] = u[i] + u[i+4];
      float ps = (u[0]+u[1]) + (u[2]+u[3]);
      lsum += xhalf_add(ps);

      // ---- pack P -> bf16 ----
      unsigned LA[2][4], LB[2][4];
      #pragma unroll
      for (int rq=0; rq<4; rq++){
        LA[0][rq] = cvtpk(s0[4*rq],   s0[4*rq+1]);
        LB[0][rq] = cvtpk(s0[4*rq+2], s0[4*rq+3]);
        LA[1][rq] = cvtpk(s1[4*rq],   s1[4*rq+1]);
        LB[1][rq] = cvtpk(s1[4*rq+2], s1[4*rq+3]);
      }

      // ---- PV from LDS V (B-operand rows = d) ----
      #pragma unroll
      for (int kt2=0; kt2<4; kt2++){
        const int kt = kt2>>1, sub = kt2&1;
        bf16x8 v0 = *(const bf16x8*)(vsb + fa[kt2]);
        bf16x8 v1 = *(const bf16x8*)(vsb + fa[kt2] + 4096);
        unsigned a0 = LA[kt][2*sub], a1 = LA[kt][2*sub+1];
        unsigned b0 = LB[kt][2*sub], b1 = LB[kt][2*sub+1];
        plswap(a0, a1);
        plswap(b0, b1);
        union { unsigned u[4]; bf16x8 v; } pf;
        pf.u[0] = a0; pf.u[1] = b0; pf.u[2] = a1; pf.u[3] = b1;
        __builtin_amdgcn_s_setprio(1);
        o0 = __builtin_amdgcn_mfma_f32_32x32x16_bf16(pf.v, v0, o0, 0,0,0);
        o1 = __builtin_amdgcn_mfma_f32_32x32x16_bf16(pf.v, v1, o1, 0,0,0);
        __builtin_amdgcn_s_setprio(0);
      }
    }
    __syncthreads();   // all reads done before next stage overwrites
  }

  // ---- epilogue: normalize + store bf16 ----
  float linv = 1.0f / lsum;
  #pragma unroll
  for (int r=0;r<16;r++){
    int qs = (r&3) + 8*(r>>2) + 4*hi;
    float lv = __shfl(linv, qs);
    size_t base = (size_t)(b*T_ + q0w + qs)*C_ + hd*D_ + l31;
    yb[base]      = f2bf(o0[r]*lv);
    yb[base + 32] = f2bf(o1[r]*lv);
  }
}

extern "C" void kernel_launch(void* const* d_in, const int* in_sizes, int n_in,
                              void* d_out, int out_size, void* d_ws, size_t ws_size,
                              hipStream_t stream){
  const float* x     = (const float*)d_in[0];
  const int*   mask  = (const int*)d_in[1];
  const float* Wqkv  = (const float*)d_in[2];
  const float* bqkv  = (const float*)d_in[3];
  const float* Wproj = (const float*)d_in[4];
  const float* bproj = (const float*)d_in[5];
  float* out = (float*)d_out;

  char* w = (char*)d_ws;
  short* xb     = (short*)w; w += (size_t)M_*C_*2;
  short* wqkvT  = (short*)w; w += (size_t)N1_*C_*2;
  short* wprojT = (short*)w; w += (size_t)C_*C_*2;
  short* qkvb   = (short*)w; w += (size_t)M_*N1_*2;
  short* vtb    = (short*)w; w += (size_t)B_*H_*D_*T_*2;
  short* yb     = (short*)w; w += (size_t)M_*C_*2;

  convx<<<dim3((M_*C_)/(256*8)), 256, 0, stream>>>(x, xb, M_*C_);
  transw<<<dim3(N1_/64, C_/64), 256, 0, stream>>>(Wqkv, wqkvT, C_, N1_);
  transw<<<dim3(C_/64,  C_/64), 256, 0, stream>>>(Wproj, wprojT, C_, C_);
  gemm_bt<1><<<dim3(N1_/128, M_/256), 512, 0, stream>>>(xb, wqkvT, bqkv, qkvb, nullptr, vtb, M_, N1_, C_);
  attn14<<<dim3(B_*H_, 16), 256, 0, stream>>>(qkvb, vtb, mask, yb);
  gemm_bt<0><<<dim3(C_/128, M_/256), 512, 0, stream>>>(yb, wprojT, bproj, nullptr, out, nullptr, M_, C_, C_);
}

// Round 16
// 179.522 us; speedup vs baseline: 1.0351x; 1.0351x over previous
//
#include <hip/hip_runtime.h>
#include <math.h>

#define B_ 4
#define T_ 2048
#define C_ 1024
#define H_ 16
#define D_ 64
#define M_ (B_*T_)      // 8192
#define N1_ (3*C_)      // 3072

typedef __attribute__((ext_vector_type(8))) short bf16x8;
typedef __attribute__((ext_vector_type(4))) short bf16x4;
typedef __attribute__((ext_vector_type(4))) float f32x4;
typedef __attribute__((ext_vector_type(16))) float f32x16;

__device__ __forceinline__ short f2bf(float f){
  union { float f; unsigned u; } v; v.f = f;
  unsigned r = (v.u + 0x7fffu + ((v.u >> 16) & 1u)) >> 16;
  return (short)r;
}

__device__ __forceinline__ unsigned cvtpk(float lo, float hi){
  unsigned r;
  asm("v_cvt_pk_bf16_f32 %0, %1, %2" : "=v"(r) : "v"(lo), "v"(hi));
  return r;
}

// v_permlane32_swap_b32: a' = {a[0:31], b[0:31]}, b' = {a[32:63], b[32:63]}
__device__ __forceinline__ void plswap(unsigned &a, unsigned &b){
  asm volatile("v_permlane32_swap_b32 %0, %1" : "+v"(a), "+v"(b));
}
__device__ __forceinline__ float xhalf_add(float x){
  unsigned a = __float_as_uint(x), b = a;
  asm volatile("v_permlane32_swap_b32 %0, %1" : "+v"(a), "+v"(b));
  return __uint_as_float(a) + __uint_as_float(b);
}

__device__ __forceinline__ void gll16(const void* g, void* l){
  __builtin_amdgcn_global_load_lds((const __attribute__((address_space(1))) void*)g,
                                   (__attribute__((address_space(3))) void*)l, 16, 0, 0);
}

// ---- convert x (f32) -> bf16 ----
__global__ __launch_bounds__(256) void convx(const float* __restrict__ x, short* __restrict__ xb, int n){
  int i = (blockIdx.x*256 + threadIdx.x)*8;
  if (i >= n) return;
  float4 a = *(const float4*)(x+i), b = *(const float4*)(x+i+4);
  bf16x8 o;
  o[0]=f2bf(a.x); o[1]=f2bf(a.y); o[2]=f2bf(a.z); o[3]=f2bf(a.w);
  o[4]=f2bf(b.x); o[5]=f2bf(b.y); o[6]=f2bf(b.z); o[7]=f2bf(b.w);
  *(bf16x8*)(xb+i) = o;
}

// ---- transpose W (K,N) f32 -> Wt (N,K) bf16 ----
__global__ __launch_bounds__(256) void transw(const float* __restrict__ W, short* __restrict__ Wt, int K, int N){
  __shared__ float tl[64][72];
  int tid = threadIdx.x;
  int n0 = blockIdx.x*64, k0 = blockIdx.y*64;
  #pragma unroll
  for (int i=0;i<4;i++){
    int row = (tid>>4) + i*16;
    int col4 = (tid&15)*4;
    float4 v = *(const float4*)&W[(size_t)(k0+row)*N + n0 + col4];
    *(float4*)&tl[row][col4] = v;
  }
  __syncthreads();
  #pragma unroll
  for (int i=0;i<2;i++){
    int nr = (tid>>3) + i*32;
    int ch = tid&7;
    bf16x8 o;
    #pragma unroll
    for (int e=0;e<8;e++) o[e] = f2bf(tl[ch*8+e][nr]);
    *(bf16x8*)&Wt[(size_t)(n0+nr)*K + k0 + ch*8] = o;
  }
}

// ---- GEMM v2: 256x128 tile, BK=64, 8 waves, triple-buffered LDS, counted vmcnt ----
// OUTBF=1 (QKV): Q columns (col < 1024) pre-scaled by cexp for attn's exp2-domain softmax.
template<int OUTBF>
__global__ __launch_bounds__(512) void gemm_bt(const short* __restrict__ A, const short* __restrict__ Bt,
           const float* __restrict__ bias, short* __restrict__ outb, float* __restrict__ outf,
           int M, int N, int K)
{
  __shared__ __attribute__((aligned(128))) char LDSC[147456];  // A:3x32KB @0, B:3x16KB @98304
  const int tid = threadIdx.x;
  const int wv = tid>>6, ln = tid&63;
  const int lnr = ln&15, lg = ln>>4;
  const int wm = wv>>1, wn = wv&1;
  const int nx = gridDim.x;
  const int nwg = nx*gridDim.y;
  const int lin = blockIdx.x + nx*blockIdx.y;
  const int swz = (lin&7)*(nwg>>3) + (lin>>3);
  const int m0 = (swz/nx)*256, n0 = (swz%nx)*128;

  const int srA = tid>>3;
  const int sg  = (tid&7) ^ (srA&7);
  const short* Ag = A  + (size_t)(m0 + srA)*K + sg*8;
  const short* Bg = Bt + (size_t)(n0 + srA)*K + sg*8;

  const int fsw = (lg ^ (lnr&7))<<4;
  const int aln = (wm*64 + lnr)*128 + fsw;
  const int bln = (wn*64 + lnr)*128 + fsw;

  auto STAGE = [&](int kt, int bi){
    const short* a = Ag + kt*64;
    const short* b = Bg + kt*64;
    char* ab = LDSC + bi*32768 + wv*1024;
    char* bb = LDSC + 98304 + bi*16384 + wv*1024;
    gll16(a,                ab);
    gll16(a + (size_t)64*K, ab + 8192);
    gll16(a + (size_t)128*K, ab + 16384);
    gll16(a + (size_t)192*K, ab + 24576);
    gll16(b,                bb);
    gll16(b + (size_t)64*K, bb + 8192);
  };

  f32x4 acc[4][4];
  #pragma unroll
  for (int i=0;i<4;i++)
    #pragma unroll
    for (int j=0;j<4;j++) acc[i][j] = (f32x4){0.f,0.f,0.f,0.f};

  const int NT = K >> 6;
  STAGE(0, 0);
  STAGE(1, 1);
  asm volatile("s_waitcnt vmcnt(6)" ::: "memory");
  __builtin_amdgcn_sched_barrier(0);
  __builtin_amdgcn_s_barrier();
  __builtin_amdgcn_sched_barrier(0);

  int cb = 0, sb = 2;
  #pragma unroll 1
  for (int kt = 0; kt < NT; kt++){
    if (kt + 2 < NT) STAGE(kt + 2, sb);

    const char* ab = LDSC + cb*32768;
    const char* bb = LDSC + 98304 + cb*16384;
    bf16x8 af[4][2], bfr[4][2];
    #pragma unroll
    for (int mi=0;mi<4;mi++)
      #pragma unroll
      for (int ks=0;ks<2;ks++)
        af[mi][ks] = *(const bf16x8*)(ab + ((aln + mi*2048) ^ (ks<<6)));
    #pragma unroll
    for (int ni=0;ni<4;ni++)
      #pragma unroll
      for (int ks=0;ks<2;ks++)
        bfr[ni][ks] = *(const bf16x8*)(bb + ((bln + ni*2048) ^ (ks<<6)));

    __builtin_amdgcn_s_setprio(1);
    #pragma unroll
    for (int mi=0;mi<4;mi++)
      #pragma unroll
      for (int ni=0;ni<4;ni++)
        #pragma unroll
        for (int ks=0;ks<2;ks++)
          acc[mi][ni] = __builtin_amdgcn_mfma_f32_16x16x32_bf16(af[mi][ks], bfr[ni][ks], acc[mi][ni], 0,0,0);
    __builtin_amdgcn_s_setprio(0);

    if (kt < NT-1){
      __builtin_amdgcn_sched_barrier(0);
      if (kt < NT-2){ asm volatile("s_waitcnt vmcnt(6)" ::: "memory"); }
      else          { asm volatile("s_waitcnt vmcnt(0)" ::: "memory"); }
      __builtin_amdgcn_sched_barrier(0);
      __builtin_amdgcn_s_barrier();
      __builtin_amdgcn_sched_barrier(0);
    }
    cb = (cb==2) ? 0 : cb+1;
    sb = (sb==2) ? 0 : sb+1;
  }

  #pragma unroll
  for (int mi=0;mi<4;mi++){
    #pragma unroll
    for (int ni=0;ni<4;ni++){
      int col = n0 + wn*64 + ni*16 + lnr;
      float bv = bias[col];
      #pragma unroll
      for (int r=0;r<4;r++){
        int row = m0 + wm*64 + mi*16 + lg*4 + r;
        float v = acc[mi][ni][r] + bv;
        if (OUTBF){
          if (col < C_) v *= 0.18033688f;   // pre-scale Q into exp2 domain
          outb[(size_t)row*N + col] = f2bf(v);
        } else {
          outf[(size_t)row*N + col] = v;
        }
      }
    }
  }
}

// ---- transpose V slice of qkv -> vt (B*H, D, T) bf16 ----
__global__ __launch_bounds__(256) void transv(const short* __restrict__ qkv, short* __restrict__ vt){
  __shared__ short tl[64][72];
  int tid = threadIdx.x;
  int t0 = blockIdx.x*64, bh = blockIdx.y;
  int b = bh>>4, h = bh&15;
  int tr = tid>>2, cc = (tid&3)*16;
  const short* src = &qkv[(size_t)(b*T_ + t0 + tr)*N1_ + 2*C_ + h*D_ + cc];
  #pragma unroll
  for (int i=0;i<4;i++){
    bf16x4 v = *(const bf16x4*)(src + i*4);
    *(bf16x4*)&tl[tr][cc + i*4] = v;
  }
  __syncthreads();
  int d = tid>>2, tc = (tid&3)*16;
  #pragma unroll
  for (int i=0;i<2;i++){
    bf16x8 o;
    #pragma unroll
    for (int e=0;e<8;e++) o[e] = tl[tc + i*8 + e][d];
    *(bf16x8*)&vt[(size_t)(bh*D_ + d)*T_ + t0 + tc + i*8] = o;
  }
}

// ---- flash attention v14: single-buffer body (best), exp2-folded softmax,
// unpaired LPT grid (1024 blocks: bh=64 x c=16), 4 waves, 16 KB LDS.
__global__ __launch_bounds__(256) void attn14(const short* __restrict__ qkv, const short* __restrict__ vt,
           const int* __restrict__ mask, short* __restrict__ yb)
{
  __shared__ short Ks[64*64];   // 8 KB, rows = key, cols swizzled
  __shared__ short Vs[64*64];   // 8 KB, rows = d,   cols swizzled
  const int tid = threadIdx.x;
  const int wv = tid>>6, ln = tid&63;
  const int l31 = ln & 31, hi = ln >> 5;
  const int bh = blockIdx.x, b = bh>>4, hd = bh&15;
  const int c = 15 - (int)blockIdx.y;    // LPT: heavy chunks dispatch first
  const float MC = 11.541561f;           // fixed softmax offset (exp2 domain)

  // staging map: thread -> (row 0..31, pre-swizzled 16B col-block)
  const int srow = tid>>3;
  const int scol = (tid&7) ^ (srow&7);
  const short* kgb = qkv + (size_t)(b*T_ + srow)*N1_ + C_ + hd*D_ + scol*8;
  const short* vgb = vt  + (size_t)((bh<<6) + srow)*T_ + scol*8;
  // fragment LDS byte addrs (loop-invariant): row l31, 16B-block (2i+hi)^(row&7)
  int fa[4];
  #pragma unroll
  for (int i=0;i<4;i++)
    fa[i] = l31*128 + ((((i<<1)+hi) ^ (l31&7)) << 4);

  char* ksb = (char*)Ks;
  char* vsb = (char*)Vs;

  const int q0w = c*128 + wv*32;
  const int ntb  = 2*c + 2;                 // block staged tiles
  const int myNt = 2*c + 1 + (wv>>1);       // wave's needed tiles

  // Q fragments (B-operand; pre-scaled by cexp in GEMM epilogue)
  bf16x8 qf[4];
  const short* qbase = qkv + (size_t)(b*T_ + q0w + l31)*N1_ + hd*D_ + hi*8;
  #pragma unroll
  for (int ds=0; ds<4; ds++) qf[ds] = *(const bf16x8*)(qbase + ds*16);

  f32x16 o0, o1;
  #pragma unroll
  for (int r=0;r<16;r++){ o0[r]=0.f; o1[r]=0.f; }
  float lsum = 0.f;

  #pragma unroll 1
  for (int jt = 0; jt < ntb; jt++){
    const int j0 = jt << 6;

    // mask (coalesced) + cooperative stage of K,V tiles
    int mval = mask[b*T_ + j0 + ln];
    const short* kg = kgb + (size_t)j0*N1_;
    const short* vg = vgb + j0;
    gll16(kg,                    ksb + wv*1024);
    gll16(kg + (size_t)32*N1_,   ksb + 4096 + wv*1024);
    gll16(vg,                    vsb + wv*1024);
    gll16(vg + (size_t)32*T_,    vsb + 4096 + wv*1024);
    unsigned long long bm = __ballot(mval != 0);
    __syncthreads();   // staged tile visible

    if (jt < myNt){
      // ---- QK^T (swapped) from LDS; acc init -MC folds softmax offset ----
      f32x16 s0, s1;
      #pragma unroll
      for (int r=0;r<16;r++){ s0[r]=-MC; s1[r]=-MC; }
      __builtin_amdgcn_s_setprio(1);
      #pragma unroll
      for (int ds=0; ds<4; ds++){
        bf16x8 k0 = *(const bf16x8*)(ksb + fa[ds]);
        bf16x8 k1 = *(const bf16x8*)(ksb + fa[ds] + 4096);
        s0 = __builtin_amdgcn_mfma_f32_32x32x16_bf16(k0, qf[ds], s0, 0,0,0);
        s1 = __builtin_amdgcn_mfma_f32_32x32x16_bf16(k1, qf[ds], s1, 0,0,0);
      }
      __builtin_amdgcn_s_setprio(0);

      // ---- masking (exp2 domain; -inf -> p=0) ----
      const int qglob = q0w + l31;
      const bool allm = (bm == ~0ull);
      if (!allm){
        #pragma unroll
        for (int r=0;r<16;r++){
          int kr = (r&3) + 8*(r>>2) + 4*hi;
          bool ok0 = (j0 + kr      <= qglob) && ((bm >> kr) & 1);
          bool ok1 = (j0 + kr + 32 <= qglob) && ((bm >> (kr+32)) & 1);
          s0[r] = ok0 ? s0[r] : -INFINITY;
          s1[r] = ok1 ? s1[r] : -INFINITY;
        }
      } else if (j0 + 63 > q0w){   // diagonal tile: causal only
        #pragma unroll
        for (int r=0;r<16;r++){
          int kr = (r&3) + 8*(r>>2) + 4*hi;
          s0[r] = (j0 + kr      <= qglob) ? s0[r] : -INFINITY;
          s1[r] = (j0 + kr + 32 <= qglob) ? s1[r] : -INFINITY;
        }
      }

      // ---- p = exp2(s) directly ----
      #pragma unroll
      for (int r=0;r<16;r++){
        s0[r] = __builtin_amdgcn_exp2f(s0[r]);
        s1[r] = __builtin_amdgcn_exp2f(s1[r]);
      }
      // tile sum
      float u[8];
      #pragma unroll
      for (int i=0;i<8;i++) u[i] = (s0[i]+s0[i+8]) + (s1[i]+s1[i+8]);
      #pragma unroll
      for (int i=0;i<4;i++) u[i] = u[i] + u[i+4];
      float ps = (u[0]+u[1]) + (u[2]+u[3]);
      lsum += xhalf_add(ps);

      // ---- pack P -> bf16 ----
      unsigned LA[2][4], LB[2][4];
      #pragma unroll
      for (int rq=0; rq<4; rq++){
        LA[0][rq] = cvtpk(s0[4*rq],   s0[4*rq+1]);
        LB[0][rq] = cvtpk(s0[4*rq+2], s0[4*rq+3]);
        LA[1][rq] = cvtpk(s1[4*rq],   s1[4*rq+1]);
        LB[1][rq] = cvtpk(s1[4*rq+2], s1[4*rq+3]);
      }

      // ---- PV from LDS V (B-operand rows = d) ----
      #pragma unroll
      for (int kt2=0; kt2<4; kt2++){
        const int kt = kt2>>1, sub = kt2&1;
        bf16x8 v0 = *(const bf16x8*)(vsb + fa[kt2]);
        bf16x8 v1 = *(const bf16x8*)(vsb + fa[kt2] + 4096);
        unsigned a0 = LA[kt][2*sub], a1 = LA[kt][2*sub+1];
        unsigned b0 = LB[kt][2*sub], b1 = LB[kt][2*sub+1];
        plswap(a0, a1);
        plswap(b0, b1);
        union { unsigned u[4]; bf16x8 v; } pf;
        pf.u[0] = a0; pf.u[1] = b0; pf.u[2] = a1; pf.u[3] = b1;
        __builtin_amdgcn_s_setprio(1);
        o0 = __builtin_amdgcn_mfma_f32_32x32x16_bf16(pf.v, v0, o0, 0,0,0);
        o1 = __builtin_amdgcn_mfma_f32_32x32x16_bf16(pf.v, v1, o1, 0,0,0);
        __builtin_amdgcn_s_setprio(0);
      }
    }
    __syncthreads();   // all reads done before next stage overwrites
  }

  // ---- epilogue: normalize + store bf16 ----
  float linv = 1.0f / lsum;
  #pragma unroll
  for (int r=0;r<16;r++){
    int qs = (r&3) + 8*(r>>2) + 4*hi;
    float lv = __shfl(linv, qs);
    size_t base = (size_t)(b*T_ + q0w + qs)*C_ + hd*D_ + l31;
    yb[base]      = f2bf(o0[r]*lv);
    yb[base + 32] = f2bf(o1[r]*lv);
  }
}

extern "C" void kernel_launch(void* const* d_in, const int* in_sizes, int n_in,
                              void* d_out, int out_size, void* d_ws, size_t ws_size,
                              hipStream_t stream){
  const float* x     = (const float*)d_in[0];
  const int*   mask  = (const int*)d_in[1];
  const float* Wqkv  = (const float*)d_in[2];
  const float* bqkv  = (const float*)d_in[3];
  const float* Wproj = (const float*)d_in[4];
  const float* bproj = (const float*)d_in[5];
  float* out = (float*)d_out;

  char* w = (char*)d_ws;
  short* xb     = (short*)w; w += (size_t)M_*C_*2;
  short* wqkvT  = (short*)w; w += (size_t)N1_*C_*2;
  short* wprojT = (short*)w; w += (size_t)C_*C_*2;
  short* qkvb   = (short*)w; w += (size_t)M_*N1_*2;
  short* vtb    = (short*)w; w += (size_t)B_*H_*D_*T_*2;
  short* yb     = (short*)w; w += (size_t)M_*C_*2;

  convx<<<dim3((M_*C_)/(256*8)), 256, 0, stream>>>(x, xb, M_*C_);
  transw<<<dim3(N1_/64, C_/64), 256, 0, stream>>>(Wqkv, wqkvT, C_, N1_);
  transw<<<dim3(C_/64,  C_/64), 256, 0, stream>>>(Wproj, wprojT, C_, C_);
  gemm_bt<1><<<dim3(N1_/128, M_/256), 512, 0, stream>>>(xb, wqkvT, bqkv, qkvb, nullptr, M_, N1_, C_);
  transv<<<dim3(T_/64, B_*H_), 256, 0, stream>>>(qkvb, vtb);
  attn14<<<dim3(B_*H_, 16), 256, 0, stream>>>(qkvb, vtb, mask, yb);
  gemm_bt<0><<<dim3(C_/128, M_/256), 512, 0, stream>>>(yb, wprojT, bproj, nullptr, out, M_, C_, C_);
}

// Round 17
// 170.392 us; speedup vs baseline: 1.0906x; 1.0536x over previous
//
#include <hip/hip_runtime.h>
#include <math.h>

#define B_ 4
#define T_ 2048
#define C_ 1024
#define H_ 16
#define D_ 64
#define M_ (B_*T_)      // 8192
#define N1_ (3*C_)      // 3072

typedef __attribute__((ext_vector_type(8))) short bf16x8;
typedef __attribute__((ext_vector_type(4))) short bf16x4;
typedef __attribute__((ext_vector_type(4))) float f32x4;
typedef __attribute__((ext_vector_type(16))) float f32x16;

__device__ __forceinline__ short f2bf(float f){
  union { float f; unsigned u; } v; v.f = f;
  unsigned r = (v.u + 0x7fffu + ((v.u >> 16) & 1u)) >> 16;
  return (short)r;
}

__device__ __forceinline__ unsigned cvtpk(float lo, float hi){
  unsigned r;
  asm("v_cvt_pk_bf16_f32 %0, %1, %2" : "=v"(r) : "v"(lo), "v"(hi));
  return r;
}

// v_permlane32_swap_b32: a' = {a[0:31], b[0:31]}, b' = {a[32:63], b[32:63]}
__device__ __forceinline__ void plswap(unsigned &a, unsigned &b){
  asm volatile("v_permlane32_swap_b32 %0, %1" : "+v"(a), "+v"(b));
}
__device__ __forceinline__ float xhalf_add(float x){
  unsigned a = __float_as_uint(x), b = a;
  asm volatile("v_permlane32_swap_b32 %0, %1" : "+v"(a), "+v"(b));
  return __uint_as_float(a) + __uint_as_float(b);
}

__device__ __forceinline__ void gll16(const void* g, void* l){
  __builtin_amdgcn_global_load_lds((const __attribute__((address_space(1))) void*)g,
                                   (__attribute__((address_space(3))) void*)l, 16, 0, 0);
}

// ---- convert x (f32) -> bf16 ----
__global__ __launch_bounds__(256) void convx(const float* __restrict__ x, short* __restrict__ xb, int n){
  int i = (blockIdx.x*256 + threadIdx.x)*8;
  if (i >= n) return;
  float4 a = *(const float4*)(x+i), b = *(const float4*)(x+i+4);
  bf16x8 o;
  o[0]=f2bf(a.x); o[1]=f2bf(a.y); o[2]=f2bf(a.z); o[3]=f2bf(a.w);
  o[4]=f2bf(b.x); o[5]=f2bf(b.y); o[6]=f2bf(b.z); o[7]=f2bf(b.w);
  *(bf16x8*)(xb+i) = o;
}

// ---- transpose W (K,N) f32 -> Wt (N,K) bf16 ----
__global__ __launch_bounds__(256) void transw(const float* __restrict__ W, short* __restrict__ Wt, int K, int N){
  __shared__ float tl[64][72];
  int tid = threadIdx.x;
  int n0 = blockIdx.x*64, k0 = blockIdx.y*64;
  #pragma unroll
  for (int i=0;i<4;i++){
    int row = (tid>>4) + i*16;
    int col4 = (tid&15)*4;
    float4 v = *(const float4*)&W[(size_t)(k0+row)*N + n0 + col4];
    *(float4*)&tl[row][col4] = v;
  }
  __syncthreads();
  #pragma unroll
  for (int i=0;i<2;i++){
    int nr = (tid>>3) + i*32;
    int ch = tid&7;
    bf16x8 o;
    #pragma unroll
    for (int e=0;e<8;e++) o[e] = f2bf(tl[ch*8+e][nr]);
    *(bf16x8*)&Wt[(size_t)(n0+nr)*K + k0 + ch*8] = o;
  }
}

// ---- GEMM 256x256: BK=64, 512 threads (8 waves 2Mx4N, wave tile 128x64),
// 2-buffer LDS 128KB, stage kt+1 at top of kt (loads hide under 64 MFMA/wave),
// one vmcnt(0)+barrier per K-tile. Q cols pre-scaled by cexp. For QKV GEMM.
__global__ __launch_bounds__(512) void gemm256(const short* __restrict__ A, const short* __restrict__ Bt,
           const float* __restrict__ bias, short* __restrict__ outb, int M, int N, int K)
{
  __shared__ __attribute__((aligned(128))) char LDSC[131072];  // A:2x32KB @0, B:2x32KB @65536
  const int tid = threadIdx.x;
  const int wv = tid>>6, ln = tid&63;
  const int lnr = ln&15, lg = ln>>4;
  const int wm = wv>>2, wn = wv&3;
  // XCD-aware bijective block swizzle (nwg = 384, %8 == 0)
  const int nx = gridDim.x;
  const int nwg = nx*gridDim.y;
  const int lin = blockIdx.x + nx*blockIdx.y;
  const int swz = (lin&7)*(nwg>>3) + (lin>>3);
  const int m0 = (swz/nx)*256, n0 = (swz%nx)*256;

  // staging: thread t -> row (t>>3)+64j, pre-swizzled 16B col-block (t&7)^(row&7)
  const int sr = tid>>3;
  const int sg = (tid&7) ^ (sr&7);
  const short* Ag = A  + (size_t)(m0 + sr)*K + sg*8;
  const short* Bg = Bt + (size_t)(n0 + sr)*K + sg*8;
  const int wv8 = wv*1024;

  // fragment read bases: row*128B + swizzled 16B block; frag (mi/ni, ks): +i*2048 ^ (ks<<6)
  const int fsw = (lg ^ (lnr&7))<<4;
  const int aln = (wm*128 + lnr)*128 + fsw;
  const int bln = (wn*64  + lnr)*128 + fsw;

  auto STAGE = [&](int kt, int bi){
    const short* a = Ag + kt*64;
    const short* b = Bg + kt*64;
    char* ab = LDSC + bi*32768 + wv8;
    char* bb = LDSC + 65536 + bi*32768 + wv8;
    gll16(a,                 ab);
    gll16(a + (size_t)64*K,  ab + 8192);
    gll16(a + (size_t)128*K, ab + 16384);
    gll16(a + (size_t)192*K, ab + 24576);
    gll16(b,                 bb);
    gll16(b + (size_t)64*K,  bb + 8192);
    gll16(b + (size_t)128*K, bb + 16384);
    gll16(b + (size_t)192*K, bb + 24576);
  };

  f32x4 acc[8][4];
  #pragma unroll
  for (int i=0;i<8;i++)
    #pragma unroll
    for (int j=0;j<4;j++) acc[i][j] = (f32x4){0.f,0.f,0.f,0.f};

  const int NT = K >> 6;   // 16
  STAGE(0, 0);
  asm volatile("s_waitcnt vmcnt(0)" ::: "memory");
  __builtin_amdgcn_sched_barrier(0);
  __builtin_amdgcn_s_barrier();
  __builtin_amdgcn_sched_barrier(0);

  #pragma unroll 1
  for (int kt = 0; kt < NT; kt++){
    const int cb = kt & 1;
    if (kt + 1 < NT) STAGE(kt + 1, cb ^ 1);

    const char* ab = LDSC + cb*32768;
    const char* bb = LDSC + 65536 + cb*32768;
    #pragma unroll
    for (int ks=0; ks<2; ks++){
      bf16x8 af[8], bfr[4];
      #pragma unroll
      for (int mi=0;mi<8;mi++) af[mi]  = *(const bf16x8*)(ab + ((aln + mi*2048) ^ (ks<<6)));
      #pragma unroll
      for (int ni=0;ni<4;ni++) bfr[ni] = *(const bf16x8*)(bb + ((bln + ni*2048) ^ (ks<<6)));
      __builtin_amdgcn_s_setprio(1);
      #pragma unroll
      for (int mi=0;mi<8;mi++)
        #pragma unroll
        for (int ni=0;ni<4;ni++)
          acc[mi][ni] = __builtin_amdgcn_mfma_f32_16x16x32_bf16(af[mi], bfr[ni], acc[mi][ni], 0,0,0);
      __builtin_amdgcn_s_setprio(0);
    }

    __builtin_amdgcn_sched_barrier(0);
    asm volatile("s_waitcnt vmcnt(0)" ::: "memory");   // kt+1's loads landed (issued ~1000cy ago)
    __builtin_amdgcn_sched_barrier(0);
    __builtin_amdgcn_s_barrier();                      // seals buf cb for restage at kt+2
    __builtin_amdgcn_sched_barrier(0);
  }

  #pragma unroll
  for (int mi=0;mi<8;mi++){
    #pragma unroll
    for (int ni=0;ni<4;ni++){
      int col = n0 + wn*64 + ni*16 + lnr;
      float bv = bias[col];
      #pragma unroll
      for (int r=0;r<4;r++){
        int row = m0 + wm*128 + mi*16 + lg*4 + r;
        float v = acc[mi][ni][r] + bv;
        if (col < C_) v *= 0.18033688f;   // pre-scale Q into exp2 domain
        outb[(size_t)row*N + col] = f2bf(v);
      }
    }
  }
}

// ---- GEMM v2 (proj): 256x128 tile, BK=64, 8 waves, triple-buffered LDS, counted vmcnt ----
__global__ __launch_bounds__(512) void gemm_proj(const short* __restrict__ A, const short* __restrict__ Bt,
           const float* __restrict__ bias, float* __restrict__ outf, int M, int N, int K)
{
  __shared__ __attribute__((aligned(128))) char LDSC[147456];  // A:3x32KB @0, B:3x16KB @98304
  const int tid = threadIdx.x;
  const int wv = tid>>6, ln = tid&63;
  const int lnr = ln&15, lg = ln>>4;
  const int wm = wv>>1, wn = wv&1;
  const int nx = gridDim.x;
  const int nwg = nx*gridDim.y;
  const int lin = blockIdx.x + nx*blockIdx.y;
  const int swz = (lin&7)*(nwg>>3) + (lin>>3);
  const int m0 = (swz/nx)*256, n0 = (swz%nx)*128;

  const int srA = tid>>3;
  const int sg  = (tid&7) ^ (srA&7);
  const short* Ag = A  + (size_t)(m0 + srA)*K + sg*8;
  const short* Bg = Bt + (size_t)(n0 + srA)*K + sg*8;

  const int fsw = (lg ^ (lnr&7))<<4;
  const int aln = (wm*64 + lnr)*128 + fsw;
  const int bln = (wn*64 + lnr)*128 + fsw;

  auto STAGE = [&](int kt, int bi){
    const short* a = Ag + kt*64;
    const short* b = Bg + kt*64;
    char* ab = LDSC + bi*32768 + wv*1024;
    char* bb = LDSC + 98304 + bi*16384 + wv*1024;
    gll16(a,                ab);
    gll16(a + (size_t)64*K, ab + 8192);
    gll16(a + (size_t)128*K, ab + 16384);
    gll16(a + (size_t)192*K, ab + 24576);
    gll16(b,                bb);
    gll16(b + (size_t)64*K, bb + 8192);
  };

  f32x4 acc[4][4];
  #pragma unroll
  for (int i=0;i<4;i++)
    #pragma unroll
    for (int j=0;j<4;j++) acc[i][j] = (f32x4){0.f,0.f,0.f,0.f};

  const int NT = K >> 6;
  STAGE(0, 0);
  STAGE(1, 1);
  asm volatile("s_waitcnt vmcnt(6)" ::: "memory");
  __builtin_amdgcn_sched_barrier(0);
  __builtin_amdgcn_s_barrier();
  __builtin_amdgcn_sched_barrier(0);

  int cb = 0, sb = 2;
  #pragma unroll 1
  for (int kt = 0; kt < NT; kt++){
    if (kt + 2 < NT) STAGE(kt + 2, sb);

    const char* ab = LDSC + cb*32768;
    const char* bb = LDSC + 98304 + cb*16384;
    bf16x8 af[4][2], bfr[4][2];
    #pragma unroll
    for (int mi=0;mi<4;mi++)
      #pragma unroll
      for (int ks=0;ks<2;ks++)
        af[mi][ks] = *(const bf16x8*)(ab + ((aln + mi*2048) ^ (ks<<6)));
    #pragma unroll
    for (int ni=0;ni<4;ni++)
      #pragma unroll
      for (int ks=0;ks<2;ks++)
        bfr[ni][ks] = *(const bf16x8*)(bb + ((bln + ni*2048) ^ (ks<<6)));

    __builtin_amdgcn_s_setprio(1);
    #pragma unroll
    for (int mi=0;mi<4;mi++)
      #pragma unroll
      for (int ni=0;ni<4;ni++)
        #pragma unroll
        for (int ks=0;ks<2;ks++)
          acc[mi][ni] = __builtin_amdgcn_mfma_f32_16x16x32_bf16(af[mi][ks], bfr[ni][ks], acc[mi][ni], 0,0,0);
    __builtin_amdgcn_s_setprio(0);

    if (kt < NT-1){
      __builtin_amdgcn_sched_barrier(0);
      if (kt < NT-2){ asm volatile("s_waitcnt vmcnt(6)" ::: "memory"); }
      else          { asm volatile("s_waitcnt vmcnt(0)" ::: "memory"); }
      __builtin_amdgcn_sched_barrier(0);
      __builtin_amdgcn_s_barrier();
      __builtin_amdgcn_sched_barrier(0);
    }
    cb = (cb==2) ? 0 : cb+1;
    sb = (sb==2) ? 0 : sb+1;
  }

  #pragma unroll
  for (int mi=0;mi<4;mi++){
    #pragma unroll
    for (int ni=0;ni<4;ni++){
      int col = n0 + wn*64 + ni*16 + lnr;
      float bv = bias[col];
      #pragma unroll
      for (int r=0;r<4;r++){
        int row = m0 + wm*64 + mi*16 + lg*4 + r;
        outf[(size_t)row*N + col] = acc[mi][ni][r] + bv;
      }
    }
  }
}

// ---- transpose V slice of qkv -> vt (B*H, D, T) bf16 ----
__global__ __launch_bounds__(256) void transv(const short* __restrict__ qkv, short* __restrict__ vt){
  __shared__ short tl[64][72];
  int tid = threadIdx.x;
  int t0 = blockIdx.x*64, bh = blockIdx.y;
  int b = bh>>4, h = bh&15;
  int tr = tid>>2, cc = (tid&3)*16;
  const short* src = &qkv[(size_t)(b*T_ + t0 + tr)*N1_ + 2*C_ + h*D_ + cc];
  #pragma unroll
  for (int i=0;i<4;i++){
    bf16x4 v = *(const bf16x4*)(src + i*4);
    *(bf16x4*)&tl[tr][cc + i*4] = v;
  }
  __syncthreads();
  int d = tid>>2, tc = (tid&3)*16;
  #pragma unroll
  for (int i=0;i<2;i++){
    bf16x8 o;
    #pragma unroll
    for (int e=0;e<8;e++) o[e] = tl[tc + i*8 + e][d];
    *(bf16x8*)&vt[(size_t)(bh*D_ + d)*T_ + t0 + tc + i*8] = o;
  }
}

// ---- flash attention v14: single-buffer body (best), exp2-folded softmax,
// unpaired LPT grid (1024 blocks: bh=64 x c=16), 4 waves, 16 KB LDS.
__global__ __launch_bounds__(256) void attn14(const short* __restrict__ qkv, const short* __restrict__ vt,
           const int* __restrict__ mask, short* __restrict__ yb)
{
  __shared__ short Ks[64*64];   // 8 KB, rows = key, cols swizzled
  __shared__ short Vs[64*64];   // 8 KB, rows = d,   cols swizzled
  const int tid = threadIdx.x;
  const int wv = tid>>6, ln = tid&63;
  const int l31 = ln & 31, hi = ln >> 5;
  const int bh = blockIdx.x, b = bh>>4, hd = bh&15;
  const int c = 15 - (int)blockIdx.y;    // LPT: heavy chunks dispatch first
  const float MC = 11.541561f;           // fixed softmax offset (exp2 domain)

  // staging map: thread -> (row 0..31, pre-swizzled 16B col-block)
  const int srow = tid>>3;
  const int scol = (tid&7) ^ (srow&7);
  const short* kgb = qkv + (size_t)(b*T_ + srow)*N1_ + C_ + hd*D_ + scol*8;
  const short* vgb = vt  + (size_t)((bh<<6) + srow)*T_ + scol*8;
  // fragment LDS byte addrs (loop-invariant): row l31, 16B-block (2i+hi)^(row&7)
  int fa[4];
  #pragma unroll
  for (int i=0;i<4;i++)
    fa[i] = l31*128 + ((((i<<1)+hi) ^ (l31&7)) << 4);

  char* ksb = (char*)Ks;
  char* vsb = (char*)Vs;

  const int q0w = c*128 + wv*32;
  const int ntb  = 2*c + 2;                 // block staged tiles
  const int myNt = 2*c + 1 + (wv>>1);       // wave's needed tiles

  // Q fragments (B-operand; pre-scaled by cexp in GEMM epilogue)
  bf16x8 qf[4];
  const short* qbase = qkv + (size_t)(b*T_ + q0w + l31)*N1_ + hd*D_ + hi*8;
  #pragma unroll
  for (int ds=0; ds<4; ds++) qf[ds] = *(const bf16x8*)(qbase + ds*16);

  f32x16 o0, o1;
  #pragma unroll
  for (int r=0;r<16;r++){ o0[r]=0.f; o1[r]=0.f; }
  float lsum = 0.f;

  #pragma unroll 1
  for (int jt = 0; jt < ntb; jt++){
    const int j0 = jt << 6;

    // mask (coalesced) + cooperative stage of K,V tiles
    int mval = mask[b*T_ + j0 + ln];
    const short* kg = kgb + (size_t)j0*N1_;
    const short* vg = vgb + j0;
    gll16(kg,                    ksb + wv*1024);
    gll16(kg + (size_t)32*N1_,   ksb + 4096 + wv*1024);
    gll16(vg,                    vsb + wv*1024);
    gll16(vg + (size_t)32*T_,    vsb + 4096 + wv*1024);
    unsigned long long bm = __ballot(mval != 0);
    __syncthreads();   // staged tile visible

    if (jt < myNt){
      // ---- QK^T (swapped) from LDS; acc init -MC folds softmax offset ----
      f32x16 s0, s1;
      #pragma unroll
      for (int r=0;r<16;r++){ s0[r]=-MC; s1[r]=-MC; }
      __builtin_amdgcn_s_setprio(1);
      #pragma unroll
      for (int ds=0; ds<4; ds++){
        bf16x8 k0 = *(const bf16x8*)(ksb + fa[ds]);
        bf16x8 k1 = *(const bf16x8*)(ksb + fa[ds] + 4096);
        s0 = __builtin_amdgcn_mfma_f32_32x32x16_bf16(k0, qf[ds], s0, 0,0,0);
        s1 = __builtin_amdgcn_mfma_f32_32x32x16_bf16(k1, qf[ds], s1, 0,0,0);
      }
      __builtin_amdgcn_s_setprio(0);

      // ---- masking (exp2 domain; -inf -> p=0) ----
      const int qglob = q0w + l31;
      const bool allm = (bm == ~0ull);
      if (!allm){
        #pragma unroll
        for (int r=0;r<16;r++){
          int kr = (r&3) + 8*(r>>2) + 4*hi;
          bool ok0 = (j0 + kr      <= qglob) && ((bm >> kr) & 1);
          bool ok1 = (j0 + kr + 32 <= qglob) && ((bm >> (kr+32)) & 1);
          s0[r] = ok0 ? s0[r] : -INFINITY;
          s1[r] = ok1 ? s1[r] : -INFINITY;
        }
      } else if (j0 + 63 > q0w){   // diagonal tile: causal only
        #pragma unroll
        for (int r=0;r<16;r++){
          int kr = (r&3) + 8*(r>>2) + 4*hi;
          s0[r] = (j0 + kr      <= qglob) ? s0[r] : -INFINITY;
          s1[r] = (j0 + kr + 32 <= qglob) ? s1[r] : -INFINITY;
        }
      }

      // ---- p = exp2(s) directly ----
      #pragma unroll
      for (int r=0;r<16;r++){
        s0[r] = __builtin_amdgcn_exp2f(s0[r]);
        s1[r] = __builtin_amdgcn_exp2f(s1[r]);
      }
      // tile sum
      float u[8];
      #pragma unroll
      for (int i=0;i<8;i++) u[i] = (s0[i]+s0[i+8]) + (s1[i]+s1[i+8]);
      #pragma unroll
      for (int i=0;i<4;i++) u[i] = u[i] + u[i+4];
      float ps = (u[0]+u[1]) + (u[2]+u[3]);
      lsum += xhalf_add(ps);

      // ---- pack P -> bf16 ----
      unsigned LA[2][4], LB[2][4];
      #pragma unroll
      for (int rq=0; rq<4; rq++){
        LA[0][rq] = cvtpk(s0[4*rq],   s0[4*rq+1]);
        LB[0][rq] = cvtpk(s0[4*rq+2], s0[4*rq+3]);
        LA[1][rq] = cvtpk(s1[4*rq],   s1[4*rq+1]);
        LB[1][rq] = cvtpk(s1[4*rq+2], s1[4*rq+3]);
      }

      // ---- PV from LDS V (B-operand rows = d) ----
      #pragma unroll
      for (int kt2=0; kt2<4; kt2++){
        const int kt = kt2>>1, sub = kt2&1;
        bf16x8 v0 = *(const bf16x8*)(vsb + fa[kt2]);
        bf16x8 v1 = *(const bf16x8*)(vsb + fa[kt2] + 4096);
        unsigned a0 = LA[kt][2*sub], a1 = LA[kt][2*sub+1];
        unsigned b0 = LB[kt][2*sub], b1 = LB[kt][2*sub+1];
        plswap(a0, a1);
        plswap(b0, b1);
        union { unsigned u[4]; bf16x8 v; } pf;
        pf.u[0] = a0; pf.u[1] = b0; pf.u[2] = a1; pf.u[3] = b1;
        __builtin_amdgcn_s_setprio(1);
        o0 = __builtin_amdgcn_mfma_f32_32x32x16_bf16(pf.v, v0, o0, 0,0,0);
        o1 = __builtin_amdgcn_mfma_f32_32x32x16_bf16(pf.v, v1, o1, 0,0,0);
        __builtin_amdgcn_s_setprio(0);
      }
    }
    __syncthreads();   // all reads done before next stage overwrites
  }

  // ---- epilogue: normalize + store bf16 ----
  float linv = 1.0f / lsum;
  #pragma unroll
  for (int r=0;r<16;r++){
    int qs = (r&3) + 8*(r>>2) + 4*hi;
    float lv = __shfl(linv, qs);
    size_t base = (size_t)(b*T_ + q0w + qs)*C_ + hd*D_ + l31;
    yb[base]      = f2bf(o0[r]*lv);
    yb[base + 32] = f2bf(o1[r]*lv);
  }
}

extern "C" void kernel_launch(void* const* d_in, const int* in_sizes, int n_in,
                              void* d_out, int out_size, void* d_ws, size_t ws_size,
                              hipStream_t stream){
  const float* x     = (const float*)d_in[0];
  const int*   mask  = (const int*)d_in[1];
  const float* Wqkv  = (const float*)d_in[2];
  const float* bqkv  = (const float*)d_in[3];
  const float* Wproj = (const float*)d_in[4];
  const float* bproj = (const float*)d_in[5];
  float* out = (float*)d_out;

  char* w = (char*)d_ws;
  short* xb     = (short*)w; w += (size_t)M_*C_*2;
  short* wqkvT  = (short*)w; w += (size_t)N1_*C_*2;
  short* wprojT = (short*)w; w += (size_t)C_*C_*2;
  short* qkvb   = (short*)w; w += (size_t)M_*N1_*2;
  short* vtb    = (short*)w; w += (size_t)B_*H_*D_*T_*2;
  short* yb     = (short*)w; w += (size_t)M_*C_*2;

  convx<<<dim3((M_*C_)/(256*8)), 256, 0, stream>>>(x, xb, M_*C_);
  transw<<<dim3(N1_/64, C_/64), 256, 0, stream>>>(Wqkv, wqkvT, C_, N1_);
  transw<<<dim3(C_/64,  C_/64), 256, 0, stream>>>(Wproj, wprojT, C_, C_);
  gemm256<<<dim3(N1_/256, M_/256), 512, 0, stream>>>(xb, wqkvT, bqkv, qkvb, M_, N1_, C_);
  transv<<<dim3(T_/64, B_*H_), 256, 0, stream>>>(qkvb, vtb);
  attn14<<<dim3(B_*H_, 16), 256, 0, stream>>>(qkvb, vtb, mask, yb);
  gemm_proj<<<dim3(C_/128, M_/256), 512, 0, stream>>>(yb, wprojT, bproj, out, M_, C_, C_);
}